// Round 1
// 89.548 us; speedup vs baseline: 1.1310x; 1.1310x over previous
//
#include <hip/hip_runtime.h>
#include <math.h>

// 2-wide fp32 vector used for packed VOP3P math (one complex amp = one VGPR pair)
typedef __attribute__((ext_vector_type(2))) float f2;

// ---------------- packed fp32 helpers (V_PK_*, CDNA2+) ----------------
// cs = (c, s) in one VGPR pair; op_sel broadcasts the needed half.
__device__ __forceinline__ f2 pk_mul_c(f2 cs, f2 a){        // (c*a.x, c*a.y)
  f2 d;
  asm("v_pk_mul_f32 %0, %1, %2 op_sel:[0,0] op_sel_hi:[0,1]"
      : "=v"(d) : "v"(cs), "v"(a));
  return d;
}
__device__ __forceinline__ f2 pk_fma_s(f2 cs, f2 b, f2 t){  // s*b + t
  f2 d;
  asm("v_pk_fma_f32 %0, %1, %2, %3 op_sel:[1,0,0] op_sel_hi:[1,1,1]"
      : "=v"(d) : "v"(cs), "v"(b), "v"(t));
  return d;
}
__device__ __forceinline__ f2 pk_fma_ns(f2 cs, f2 b, f2 t){ // -s*b + t
  f2 d;
  asm("v_pk_fma_f32 %0, %1, %2, %3 op_sel:[1,0,0] op_sel_hi:[1,1,1] neg_lo:[1,0,0] neg_hi:[1,0,0]"
      : "=v"(d) : "v"(cs), "v"(b), "v"(t));
  return d;
}
// RX cross form: (s*b.y + t.x, -s*b.x + t.y)  [op_sel swaps b's halves, neg on hi]
__device__ __forceinline__ f2 pk_fma_sxn(f2 cs, f2 b, f2 t){
  f2 d;
  asm("v_pk_fma_f32 %0, %1, %2, %3 op_sel:[1,1,0] op_sel_hi:[1,0,1] neg_hi:[0,1,0]"
      : "=v"(d) : "v"(cs), "v"(b), "v"(t));
  return d;
}
__device__ __forceinline__ f2 pk_fma_lo(f2 w, f2 b, f2 t){  // w.x*b + t (broadcast lo)
  f2 d;
  asm("v_pk_fma_f32 %0, %1, %2, %3 op_sel:[0,0,0] op_sel_hi:[0,1,1]"
      : "=v"(d) : "v"(w), "v"(b), "v"(t));
  return d;
}

// ---------------- state layout ----------------
// 1024-amp state per wave: 16 f2 regs x 64 lanes.
// state index n (10 bits): reg r = n[6:3] (r3=n6,r2=n5,r1=n4,r0=n3)
// lane bits: n7->L0, n8->L1, n2->L2, n1->L3, n0->L4, n9->L5
template<int B> struct LSH {
  static constexpr int v = (B==7)?0 : (B==8)?1 : (B==2)?2 : (B==1)?3 : (B==0)?4 : 5;
};

// lane exchange across state bit PB (PB in {0,1,2,7,8,9})
template<int PB>
__device__ __forceinline__ float lx(float v){
  if constexpr (PB == 7)       // lane xor 1: DPP quad_perm [1,0,3,2]
    return __int_as_float(__builtin_amdgcn_update_dpp(
        __float_as_int(v), __float_as_int(v), 0xB1, 0xF, 0xF, false));
  else if constexpr (PB == 8)  // lane xor 2: DPP quad_perm [2,3,0,1]
    return __int_as_float(__builtin_amdgcn_update_dpp(
        __float_as_int(v), __float_as_int(v), 0x4E, 0xF, 0xF, false));
  else if constexpr (PB == 2)  // lane xor 4
    return __int_as_float(__builtin_amdgcn_ds_swizzle(__float_as_int(v), 0x101F));
  else if constexpr (PB == 1)  // lane xor 8
    return __int_as_float(__builtin_amdgcn_ds_swizzle(__float_as_int(v), 0x201F));
  else if constexpr (PB == 0)  // lane xor 16
    return __int_as_float(__builtin_amdgcn_ds_swizzle(__float_as_int(v), 0x401F));
  else                         // PB == 9: lane xor 32
    return __shfl_xor(v, 32, 64);
}

// Rotation (RY or RX) pairing amplitudes across state bit PB, optional CNOT
// control on state bit CB (control=1 => inputs swapped). CB=-1: none.
// Packed: 2 pk_mul + 2 pk_fma per pair (reg pass), 1+1 per reg (lane pass) —
// bit-identical rounding to the previous scalar mul->fma sequence.
template<int PB, int CB, bool ISRX>
__device__ __forceinline__ void gate_pass(f2* A, f2 cs, int lane)
{
  if constexpr (PB >= 3 && PB <= 6) {
    constexpr int RM = 1 << (PB - 3);
    bool cl = false;
    if constexpr (CB >= 0 && !(CB >= 3 && CB <= 6))
      cl = (lane >> LSH<CB>::v) & 1;
    #pragma unroll
    for (int r = 0; r < 16; ++r) {
      if (r & RM) continue;
      f2 a0 = A[r], a1 = A[r | RM];
      bool sw;
      if constexpr (CB < 0) sw = false;
      else if constexpr (CB >= 3 && CB <= 6) sw = (r >> (CB - 3)) & 1;
      else sw = cl;
      f2 i0, i1;
      i0.x = sw ? a1.x : a0.x;  i0.y = sw ? a1.y : a0.y;
      i1.x = sw ? a0.x : a1.x;  i1.y = sw ? a0.y : a1.y;
      if constexpr (ISRX) {
        A[r]      = pk_fma_sxn(cs, i1, pk_mul_c(cs, i0));
        A[r | RM] = pk_fma_sxn(cs, i0, pk_mul_c(cs, i1));
      } else {
        A[r]      = pk_fma_ns(cs, i1, pk_mul_c(cs, i0));
        A[r | RM] = pk_fma_s (cs, i0, pk_mul_c(cs, i1));
      }
    }
  } else {
    const int mybit = (lane >> LSH<PB>::v) & 1;
    f2 sv;                                   // RY own-sign (ssy, ssy); unused for RX
    if constexpr (!ISRX) {
      float ssy = mybit ? cs.y : -cs.y;
      sv.x = ssy; sv.y = ssy;
    }
    #pragma unroll
    for (int r = 0; r < 16; ++r) {
      f2 p;
      p.x = lx<PB>(A[r].x);
      p.y = lx<PB>(A[r].y);
      bool sw = false;
      if constexpr (CB >= 3 && CB <= 6) sw = (r >> (CB - 3)) & 1;   // compile-time
      f2 u, v;
      u.x = sw ? p.x : A[r].x;  u.y = sw ? p.y : A[r].y;
      v.x = sw ? A[r].x : p.x;  v.y = sw ? A[r].y : p.y;
      if constexpr (ISRX) A[r] = pk_fma_sxn(cs, v, pk_mul_c(cs, u));
      else                A[r] = pk_fma_lo (sv, v, pk_mul_c(cs, u));
    }
  }
}

// One fused conv iteration, window bits LO..LO+4 (bit LO+4 = wire i):
// RY0@i; RY1@i+3 ctl i; RY2@i+1; RX0@i+4 ctl i+1; RX1@i+1 ctl i+3.
template<int LO>
__device__ __forceinline__ void iter_reg(f2* A, int lane,
    f2 cs0, f2 cs1, f2 cs2, f2 csx, f2 cs4)
{
  gate_pass<LO+4, -1,   false>(A, cs0, lane);
  gate_pass<LO+1, LO+4, false>(A, cs1, lane);
  gate_pass<LO+3, -1,   false>(A, cs2, lane);
  gate_pass<LO,   LO+3, true >(A, csx, lane);
  gate_pass<LO+3, LO+1, true >(A, cs4, lane);
}

#define RUN6(A) \
  iter_reg<5>(A, lane, cs0,cs1,cs2,csx,cs4); \
  iter_reg<4>(A, lane, cs0,cs1,cs2,csx,cs4); \
  iter_reg<3>(A, lane, cs0,cs1,cs2,csx,cs4); \
  iter_reg<2>(A, lane, cs0,cs1,cs2,csx,cs4); \
  iter_reg<1>(A, lane, cs0,cs1,cs2,csx,cs4); \
  iter_reg<0>(A, lane, cs0,cs1,cs2,csx,cs4);

__device__ __forceinline__ float wave_sum(float v){
  v += lx<7>(v);            // xor1 (DPP)
  v += lx<8>(v);            // xor2 (DPP)
  v += lx<2>(v);            // xor4
  v += lx<1>(v);            // xor8
  v += lx<0>(v);            // xor16
  v += __shfl_xor(v, 32, 64);
  return v;
}

__global__ __launch_bounds__(256) void sim_kernel(
    const float* __restrict__ x, const float* __restrict__ kp,
    float* __restrict__ pacc)   // 512 rows x 12 floats, row = blockIdx (pair*16 + cb)
{
  // 4 waves x 1024 f2 (8192 f) + 4 x 32 angles (128 f) + 4 x 12 block-reduce staging
  __shared__ __align__(16) float lds[8368];

  const int tid = threadIdx.x, wv = tid >> 6, lane = tid & 63;
  const int gw = blockIdx.x * 4 + wv;
  const int pair = gw >> 6;      // k*16 + b
  const int chunk = gw & 63;     // wires 0..5: wire w = (chunk>>(5-w))&1
  const int b = pair & 15, k = pair >> 4;

  f2*    P    = (f2*)&lds[wv * 2048];
  float* angw = &lds[8192 + wv * 32];
  float* stg  = &lds[8320];

  // ---- avgpool -> (cos,sin) of half-angles, 16 wires ----
  // lane q in [0,4) sums rows {q, q+4} of its 7x7 window (no div/mod in the loop)
  {
    int a = lane >> 2, q = lane & 3;
    int ii = a >> 2, jj = a & 3;
    const float* xb = x + b*784 + ii*7*28 + jj*7;
    const float* r0 = xb + q*28;
    float s = r0[0]+r0[1]+r0[2]+r0[3]+r0[4]+r0[5]+r0[6];
    if (q < 3){
      const float* r1 = xb + (q+4)*28;
      s += r1[0]+r1[1]+r1[2]+r1[3]+r1[4]+r1[5]+r1[6];
    }
    s += __shfl_xor(s, 1, 64);
    s += __shfl_xor(s, 2, 64);
    float ang = s * (1.0f/49.0f) * 0.5f;
    if (q == 0){ angw[a*2] = cosf(ang); angw[a*2+1] = sinf(ang); }
  }

  const float* p5 = kp + k*5;
  f2 cs0, cs1, cs2, csx, cs4;
  cs0.x = cosf(p5[0]*0.5f); cs0.y = sinf(p5[0]*0.5f);
  cs1.x = cosf(p5[1]*0.5f); cs1.y = sinf(p5[1]*0.5f);
  cs2.x = cosf(p5[2]*0.5f); cs2.y = sinf(p5[2]*0.5f);
  csx.x = cosf(p5[3]*0.5f); csx.y = sinf(p5[3]*0.5f);
  cs4.x = cosf(p5[4]*0.5f); cs4.y = sinf(p5[4]*0.5f);

  __threadfence_block();

  f2 A[16];

  // ---- stage 1: Psi over wires 0..9 (wire w -> n bit 9-w) ----
  {
    float lp = 1.f;
    lp *= ((lane>>5)&1) ? angw[1]  : angw[0];    // wire0 (n9=L5)
    lp *= ((lane>>1)&1) ? angw[3]  : angw[2];    // wire1 (n8=L1)
    lp *= ( lane    &1) ? angw[5]  : angw[4];    // wire2 (n7=L0)
    lp *= ((lane>>2)&1) ? angw[15] : angw[14];   // wire7 (n2=L2)
    lp *= ((lane>>3)&1) ? angw[17] : angw[16];   // wire8 (n1=L3)
    lp *= ((lane>>4)&1) ? angw[19] : angw[18];   // wire9 (n0=L4)
    float c3 = angw[6],  s3 = angw[7];   // wire3 (r3)
    float c4w= angw[8],  s4w= angw[9];   // wire4 (r2)
    float c5 = angw[10], s5 = angw[11];  // wire5 (r1)
    float c6 = angw[12], s6 = angw[13];  // wire6 (r0)
    #pragma unroll
    for (int r = 0; r < 16; ++r){
      float rp = ((r&8)? s3:c3) * ((r&4)? s4w:c4w) * ((r&2)? s5:c5) * ((r&1)? s6:c6);
      A[r].x = lp * rp; A[r].y = 0.f;
    }
  }
  RUN6(A);   // iterations 0..5 (wire w -> bit 9-w, iter i: LO = 5-i)

  // ---- dump Psi to per-wave LDS, gather this chunk's 16-value window ----
  #pragma unroll
  for (int r = 0; r < 16; ++r) P[(r << 6) | lane] = A[r];
  __threadfence_block();
  {
    // needed Psi index h = (chunk<<4) | j ; j3=wire6, j2=wire7, j1=wire8, j0=wire9
    // stage-3 state: wire6->n9(L5), wire7->n8(L1), wire8->n7(L0), wire9->n6(r3)
    int jc = (((lane>>5)&1) << 2) | (((lane>>1)&1) << 1) | (lane & 1);
    int h0 = (chunk << 4) | (jc << 1);
    int r0_ = (h0 >> 3) & 15;
    int l0_ = ((h0>>7)&1) | (((h0>>8)&1)<<1) | (((h0>>2)&1)<<2)
            | (((h0>>1)&1)<<3) | ((h0&1)<<4) | (((h0>>9)&1)<<5);
    f2 ps0 = P[(r0_ << 6) | l0_];
    f2 ps1 = P[(r0_ << 6) | l0_ | 16];   // h0|1 flips n bit0 -> lane bit 4

    // Pre over wires 10..15: wire10->r2, wire11->r1, wire12->r0,
    //                        wire13->L2, wire14->L3, wire15->L4
    float c10 = angw[20], s10 = angw[21];
    float c11 = angw[22], s11 = angw[23];
    float c12 = angw[24], s12 = angw[25];
    float preL = 1.f;
    preL *= ((lane>>2)&1) ? angw[27] : angw[26]; // wire13
    preL *= ((lane>>3)&1) ? angw[29] : angw[28]; // wire14
    preL *= ((lane>>4)&1) ? angw[31] : angw[30]; // wire15
    #pragma unroll
    for (int r = 0; r < 16; ++r){
      float f = preL * (((r&4)? s10:c10) * ((r&2)? s11:c11) * ((r&1)? s12:c12));
      f2 v = (r & 8) ? ps1 : ps0;
      A[r].x = v.x * f; A[r].y = v.y * f;
    }
  }

  RUN6(A);   // iterations 6..11 (wire w -> local bit 15-w, iter i: LO = 11-i)

  // ---- measurement: E[Z_w], final CNOT block folded into parity masks ----
  float out12[12];
  {
    int idx_hi = (chunk << 10)
      | (((lane>>5)&1) << 9) | (((lane>>1)&1) << 8) | ((lane & 1) << 7)
      | (((lane>>2)&1) << 2) | (((lane>>3)&1) << 1) | ((lane>>4)&1);
    float p[16];
    #pragma unroll
    for (int r = 0; r < 16; ++r) p[r] = A[r].x*A[r].x + A[r].y*A[r].y;
    #pragma unroll
    for (int w = 0; w < 12; ++w){
      float s = 0.f;
      #pragma unroll
      for (int r = 0; r < 16; ++r)
        s += (__popc((r << 3) & (27 << (11 - w))) & 1) ? -p[r] : p[r];
      s = (__popc(idx_hi & (27 << (11 - w))) & 1) ? -s : s;
      out12[w] = wave_sum(s);
    }
  }

  // ---- block-level reduce: 4 waves (4 chunks of the same pair) -> 1 row ----
  // stg region is dedicated (outside P/angw), so only one barrier is needed.
  if (lane == 0){
    #pragma unroll
    for (int w = 0; w < 12; ++w) stg[wv*12 + w] = out12[w];
  }
  __syncthreads();
  if (wv == 0 && lane < 12){
    float t = stg[lane] + stg[12+lane] + stg[24+lane] + stg[36+lane];
    pacc[blockIdx.x*12 + lane] = t;   // row = pair*16 + (chunk>>2) = blockIdx
  }
}

// One block per batch element b: reduce 2x16 pacc rows -> 24 feats, then 3 FC layers.
__global__ __launch_bounds__(256) void mlp_kernel(
    const float* __restrict__ pacc,
    const float* __restrict__ w1, const float* __restrict__ b1,
    const float* __restrict__ w2, const float* __restrict__ b2,
    const float* __restrict__ w3, const float* __restrict__ b3,
    float* __restrict__ out)
{
  __shared__ __align__(16) float feats[24];
  __shared__ __align__(16) float h1[128];
  __shared__ __align__(16) float h2[64];
  const int tid = threadIdx.x, b = blockIdx.x;

  {
    int f = tid >> 3, part = tid & 7;     // 8 threads per feature
    if (f < 24){
      int kk = (f >= 12) ? 1 : 0, w = f - kk*12;
      int pair = kk*16 + b;
      const float* base = pacc + pair*16*12 + w;
      float s = base[part*12] + base[(part+8)*12];
      s += __shfl_xor(s, 1, 64);
      s += __shfl_xor(s, 2, 64);
      s += __shfl_xor(s, 4, 64);
      if (part == 0) feats[f] = s;
    }
  }
  __syncthreads();

  if (tid < 128){
    const float4* wr = (const float4*)(w1 + tid*24);
    const float4* fr = (const float4*)feats;
    float s = b1[tid];
    #pragma unroll
    for (int q = 0; q < 6; ++q){
      float4 a = fr[q], ww = wr[q];
      s += a.x*ww.x + a.y*ww.y + a.z*ww.z + a.w*ww.w;
    }
    h1[tid] = fmaxf(s, 0.f);
  }
  __syncthreads();
  if (tid < 64){
    const float4* wr = (const float4*)(w2 + tid*128);
    const float4* hr = (const float4*)h1;
    float s = b2[tid];
    #pragma unroll
    for (int q = 0; q < 32; ++q){
      float4 a = hr[q], ww = wr[q];
      s += a.x*ww.x + a.y*ww.y + a.z*ww.z + a.w*ww.w;
    }
    h2[tid] = fmaxf(s, 0.f);
  }
  __syncthreads();
  if (tid < 4){
    const float4* wr = (const float4*)(w3 + tid*64);
    const float4* hr = (const float4*)h2;
    float s = b3[tid];
    #pragma unroll
    for (int q = 0; q < 16; ++q){
      float4 a = hr[q], ww = wr[q];
      s += a.x*ww.x + a.y*ww.y + a.z*ww.z + a.w*ww.w;
    }
    out[b*4 + tid] = s;
  }
}

extern "C" void kernel_launch(void* const* d_in, const int* in_sizes, int n_in,
                              void* d_out, int out_size, void* d_ws, size_t ws_size,
                              hipStream_t stream) {
  const float* x  = (const float*)d_in[0];
  const float* kp = (const float*)d_in[1];
  const float* w1 = (const float*)d_in[2];
  const float* b1 = (const float*)d_in[3];
  const float* w2 = (const float*)d_in[4];
  const float* b2 = (const float*)d_in[5];
  const float* w3 = (const float*)d_in[6];
  const float* b3 = (const float*)d_in[7];
  float* out  = (float*)d_out;
  float* pacc = (float*)d_ws;   // 512*12 floats = 24 KB

  sim_kernel<<<512, 256, 0, stream>>>(x, kp, pacc);
  mlp_kernel<<<16, 256, 0, stream>>>(pacc, w1, b1, w2, b2, w3, b3, out);
}